// Round 5
// baseline (4043.291 us; speedup 1.0000x reference)
//
#include <hip/hip_runtime.h>

// Net_39135742001869: S2VT video-caption LSTM (enc 80 + dec 39 steps), bf16 MFMA.
// R5: wave-granular barrier-free recurrence; fragment-packed weights/X from L2; no LDS.

typedef unsigned short u16;
typedef unsigned int u32;
typedef unsigned long long u64;
typedef __attribute__((ext_vector_type(8))) short s8v;   // 8 x bf16 (as short)
typedef __attribute__((ext_vector_type(4))) float f4v;   // MFMA accumulator

#define VOC   6000
#define VOCP  6144        // padded to multiple of 256
#define HSTR  65536       // 256*256 h-history slot stride (elements)
#define XSTR  262144      // 8*8*64*64 X-fragment step stride (elements)

__device__ __forceinline__ u16 f2b(float f) {
  unsigned u = __float_as_uint(f);
  unsigned r = (u + 0x7fffu + ((u >> 16) & 1u)) >> 16;   // RNE f32->bf16
  return (u16)r;
}
__device__ __forceinline__ float b2f(u16 u) {
  return __uint_as_float(((unsigned)u) << 16);
}
__device__ __forceinline__ float sigm(float x) { return 1.f / (1.f + __expf(-x)); }
__device__ __forceinline__ float tanh_f(float x) {
  float e = __expf(-2.f * fabsf(x));
  float t = (1.f - e) / (1.f + e);
  return x >= 0.f ? t : -t;
}

// ---------------- f32 -> bf16 elementwise conversion (8 elems/thread) ------------------
__global__ __launch_bounds__(256) void conv_f2b(const float* __restrict__ src,
                                                u16* __restrict__ dst, long n) {
  long stride = (long)gridDim.x * 2048;
  for (long i = ((long)blockIdx.x * 256 + threadIdx.x) * 8; i < n; i += stride) {
    float4 a = *(const float4*)(src + i);
    float4 b = *(const float4*)(src + i + 4);
    unsigned w0 = (unsigned)f2b(a.x) | ((unsigned)f2b(a.y) << 16);
    unsigned w1 = (unsigned)f2b(a.z) | ((unsigned)f2b(a.w) << 16);
    unsigned w2 = (unsigned)f2b(b.x) | ((unsigned)f2b(b.y) << 16);
    unsigned w3 = (unsigned)f2b(b.z) | ((unsigned)f2b(b.w) << 16);
    *(int4*)(dst + i) = make_int4((int)w0, (int)w1, (int)w2, (int)w3);
  }
}

// ---------------- weight pack (f32 -> bf16, strided slice + zero pad rows) -------------
__global__ void pack_bf16(u16* __restrict__ dst, int dld, int doff,
                          const float* __restrict__ src, int sld, int soff,
                          int Wc, int R, int Rsrc) {
  int i = blockIdx.x * 256 + threadIdx.x;
  if (i >= Wc * R) return;
  int r = i / Wc, c = i - r * Wc;
  float v = (r < Rsrc) ? src[(size_t)r * sld + soff + c] : 0.f;
  dst[(size_t)r * dld + doff + c] = f2b(v);
}

// ---------------- recurrence-weight MFMA-fragment pack ---------------------------------
// dst[cs8(8)][ct(8)][kk(KK)][lane(64)][8 u16]; gate-row g = (ct>>1)*256 + cs8*32 +
// (ct&1)*16 + (lane&15); k = kk*32 + (lane>>4)*8 + e.
// KK=8: src = W_hh1 [1024][256].  KK=16: k<256 -> W_ih2[g][256+k], else W_hh2[g][k-256].
template <int KK>
__global__ __launch_bounds__(256) void wfrag_pack(u16* __restrict__ dst,
                                                  const float* __restrict__ srcA,
                                                  const float* __restrict__ srcB) {
  int idx = blockIdx.x * 256 + threadIdx.x;
  if (idx >= 8 * 8 * KK * 64) return;
  int lane = idx & 63;
  int t = idx >> 6;
  int kk = t % KK; t /= KK;
  int ct = t & 7;
  int cs8 = t >> 3;
  int g = (ct >> 1) * 256 + cs8 * 32 + (ct & 1) * 16 + (lane & 15);
  int k0 = kk * 32 + (lane >> 4) * 8;
  u16 out[8];
#pragma unroll
  for (int e = 0; e < 8; ++e) {
    int k = k0 + e;
    float v;
    if (KK == 8) v = srcA[(size_t)g * 256 + k];
    else v = (k < 256) ? srcA[(size_t)g * 512 + 256 + k]
                       : srcB[(size_t)g * 256 + (k - 256)];
    out[e] = f2b(v);
  }
  *(int4*)(dst + (size_t)idx * 8) = *(const int4*)out;
}

__global__ void bias_setup(const float* __restrict__ bi1, const float* __restrict__ bh1,
                           const float* __restrict__ bi2, const float* __restrict__ bh2,
                           const float* __restrict__ bo,
                           float* __restrict__ b1s, float* __restrict__ b2s,
                           float* __restrict__ bop) {
  int i = blockIdx.x * 256 + threadIdx.x;
  if (i < 1024) { b1s[i] = bi1[i] + bh1[i]; b2s[i] = bi2[i] + bh2[i]; }
  if (i < VOCP) bop[i] = (i < VOC) ? bo[i] : -1e30f;   // -inf-ish pad: excluded from LSE
}

// ---------------- targets = argmax(caption_one_hot[b, d+1, :]) -------------------------
__global__ __launch_bounds__(256) void argmax_kernel(const float* __restrict__ coh,
                                                     int* __restrict__ tgt) {
  const int d = blockIdx.x >> 8;       // 0..38
  const int b = blockIdx.x & 255;
  const float4* row = (const float4*)(coh + ((size_t)b * 40 + (d + 1)) * VOC);
  float best = -3.4e38f; int bi = 0;
  for (int v = threadIdx.x; v < VOC / 4; v += 256) {
    float4 x = row[v];
    float vals[4] = {x.x, x.y, x.z, x.w};
#pragma unroll
    for (int j = 0; j < 4; ++j)
      if (vals[j] > best) { best = vals[j]; bi = v * 4 + j; }
  }
#pragma unroll
  for (int o = 1; o < 64; o <<= 1) {
    float ov = __shfl_xor(best, o);
    int   oi = __shfl_xor(bi, o);
    if (ov > best || (ov == best && oi < bi)) { best = ov; bi = oi; }
  }
  __shared__ float sv[4]; __shared__ int si[4];
  if ((threadIdx.x & 63) == 0) { sv[threadIdx.x >> 6] = best; si[threadIdx.x >> 6] = bi; }
  __syncthreads();
  if (threadIdx.x == 0) {
    for (int i = 1; i < 4; ++i)
      if (sv[i] > best || (sv[i] == best && si[i] < bi)) { best = sv[i]; bi = si[i]; }
    tgt[blockIdx.x] = bi;              // layout [d][b]
  }
}

// ---------------- GEMM: acc = A_bf16[M][K] * Bw_bf16[N][K]^T (+bias), 3 epilogues ------
// grid = (M/128, N/256); K multiple of 64. XCD-bijective swizzle on the m-tile index.
// MODE 0/1: write X fragments (per-wave layout) for the recurrence.
// MODE 2: fused NLL partials: per (row, n-half-tile) write (max, expsum) + target logit.
template <int MODE>
__global__ __launch_bounds__(256) void gemm_bb(
    const u16* __restrict__ A, const u16* __restrict__ Bw,
    const float* __restrict__ bias, void* __restrict__ out0,
    float* __restrict__ ps, float* __restrict__ tgtlog, const int* __restrict__ tgt,
    int K, int moff)
{
  const int nx = gridDim.x;
  const int qq = nx >> 3, rm = nx & 7;
  const int xcd = (int)blockIdx.x & 7, pos = (int)blockIdx.x >> 3;
  const int mt = (xcd < rm) ? (xcd * (qq + 1) + pos)
                            : (rm * (qq + 1) + (xcd - rm) * qq + pos);
  const int m0 = mt * 128;
  const int n0 = blockIdx.y * 256;
  const int tid = threadIdx.x;
  const int lane = tid & 63;
  const int wid = tid >> 6;
  const int wm = wid >> 1, wn = wid & 1;
  const int fr = lane & 15;
  const int fk = (lane >> 4) * 8;
  const int rq = lane >> 4;

  __shared__ u16 As[128][72];   // pad: stride 144B -> benign 2-way bank aliasing
  __shared__ u16 Bs[256][72];
  f4v acc[4][8] = {};

  const int ar = tid >> 1, ac = (tid & 1) * 32;
  int4 av[4], bv[8];
  {
    const u16* ap = A + (size_t)(m0 + ar) * K + ac;
    const u16* bp = Bw + (size_t)(n0 + tid) * K;
#pragma unroll
    for (int v = 0; v < 4; ++v) av[v] = *(const int4*)(ap + v * 8);
#pragma unroll
    for (int v = 0; v < 8; ++v) bv[v] = *(const int4*)(bp + v * 8);
  }
#pragma unroll 1
  for (int k0 = 0; k0 < K; k0 += 64) {
    __syncthreads();
#pragma unroll
    for (int v = 0; v < 4; ++v) *(int4*)&As[ar][ac + v * 8] = av[v];
#pragma unroll
    for (int v = 0; v < 8; ++v) *(int4*)&Bs[tid][v * 8] = bv[v];
    __syncthreads();
    if (k0 + 64 < K) {
      const u16* ap = A + (size_t)(m0 + ar) * K + k0 + 64 + ac;
      const u16* bp = Bw + (size_t)(n0 + tid) * K + k0 + 64;
#pragma unroll
      for (int v = 0; v < 4; ++v) av[v] = *(const int4*)(ap + v * 8);
#pragma unroll
      for (int v = 0; v < 8; ++v) bv[v] = *(const int4*)(bp + v * 8);
    }
#pragma unroll
    for (int ks = 0; ks < 2; ++ks) {
      const int kb = ks * 32 + fk;
      s8v a[4], b[8];
#pragma unroll
      for (int i = 0; i < 4; ++i) a[i] = *(const s8v*)&As[wm * 64 + i * 16 + fr][kb];
#pragma unroll
      for (int j = 0; j < 8; ++j) b[j] = *(const s8v*)&Bs[wn * 128 + j * 16 + fr][kb];
#pragma unroll
      for (int i = 0; i < 4; ++i)
#pragma unroll
        for (int j = 0; j < 8; ++j)
          acc[i][j] = __builtin_amdgcn_mfma_f32_16x16x32_bf16(a[i], b[j], acc[i][j], 0, 0, 0);
    }
  }

  float bz[8];
#pragma unroll
  for (int j = 0; j < 8; ++j) bz[j] = bias[n0 + wn * 128 + j * 16 + fr];

  if (MODE == 2) {
    const int tile = blockIdx.y * 2 + wn;
    float* pm = (float*)out0;
#pragma unroll
    for (int i = 0; i < 4; ++i) {
#pragma unroll
      for (int r = 0; r < 4; ++r) {
        const int row = m0 + wm * 64 + i * 16 + rq * 4 + r;
        const int tg = tgt[row];
        float vj[8]; float m = -1e30f;
#pragma unroll
        for (int j = 0; j < 8; ++j) {
          const int n = n0 + wn * 128 + j * 16 + fr;
          float v = acc[i][j][r] + bz[j];
          vj[j] = v;
          m = fmaxf(m, v);
          if (n == tg) tgtlog[row] = v;
        }
#pragma unroll
        for (int o = 1; o < 16; o <<= 1) m = fmaxf(m, __shfl_xor(m, o));
        float s = 0.f;
#pragma unroll
        for (int j = 0; j < 8; ++j) s += __expf(vj[j] - m);
#pragma unroll
        for (int o = 1; o < 16; o <<= 1) s += __shfl_xor(s, o);
        if (fr == 0) { pm[(size_t)row * 48 + tile] = m; ps[(size_t)row * 48 + tile] = s; }
      }
    }
  } else {
    // X fragment epilogue: Xf[tt][rg2][c8][lane2][64], elem = ((ii*2+cth)*4+q)*4+rr
    u16* X = (u16*)out0;
    const int TT = (MODE == 0) ? 80 : 40;
#pragma unroll
    for (int i = 0; i < 4; ++i) {
#pragma unroll
      for (int r = 0; r < 4; ++r) {
        const int m = moff + m0 + wm * 64 + i * 16 + rq * 4 + r;
        const int bat = m / TT;
        const int tt = m - bat * TT;
        const int rg2 = bat >> 5, ii = (bat >> 4) & 1;
        const int lbase = ((bat >> 2) & 3) * 16;
        const int rr = bat & 3;
#pragma unroll
        for (int j = 0; j < 8; ++j) {
          const int n = n0 + wn * 128 + j * 16 + fr;
          const int q = n >> 8, nc = n & 255;
          const int c8 = nc >> 5, cth = (nc >> 4) & 1;
          const int lane2 = lbase + (nc & 15);
          const int elem = ((ii * 2 + cth) * 4 + q) * 4 + rr;
          X[((((size_t)tt * 8 + rg2) * 8 + c8) * 64 + lane2) * 64 + elem] =
              f2b(acc[i][j][r] + bz[j]);
        }
      }
    }
  }
}

// ---------------- wave-granular barrier-free recurrence --------------------------------
// 128 blocks x 64 threads (1 wave each). Blocks 0..63: phase1 (LSTM1), 64..127: phase2.
// Wave (rg2 0..7, cs8 0..7) owns batch rows rg2*32..+32 x h-cols cs8*32..+32.
// The 8 rg2 row-groups are fully independent chains (batch rows never interact).
// h histories [120][256][256] bf16; slot s+1 = h(s); slot 0 = zeros.
// Producer: sc1 h-stores -> vmcnt(0) -> relaxed flag f[rg2*8+cs8] = s+1 (single wave, no
// barriers). Consumer polls the 8 flags of its rg2 group (lanes 0..15, read-only).
__global__ __launch_bounds__(64, 1) void recur_kernel(
    const u16* __restrict__ X1f,      // [80][8][8][64][64] bf16 fragments, bias folded
    const u16* __restrict__ Xcf,      // [40][8][8][64][64]
    const float* __restrict__ b1sum, const float* __restrict__ b2sum,
    const u16* __restrict__ Wf1,      // [8][8][8][64][8]  (K=256)
    const u16* __restrict__ Wf2,      // [8][8][16][64][8] (K=512: h1 | h2)
    u16* __restrict__ h1hist, u16* __restrict__ h2hist,
    u32* __restrict__ f1, u32* __restrict__ f2)
{
  const int lane = threadIdx.x;
  const int fr = lane & 15, rq = lane >> 4;
  const bool p2 = blockIdx.x >= 64;
  const int bb = p2 ? (int)blockIdx.x - 64 : (int)blockIdx.x;
  const int rg2 = bb >> 3, cs8 = bb & 7;
  const int KK = p2 ? 16 : 8;
  const u16* Wf = p2 ? Wf2 : Wf1;
  const int rowbase = rg2 * 32;
  const int colbase = cs8 * 32;

  float br[2][4];
  {
    const float* bs = p2 ? b2sum : b1sum;
#pragma unroll
    for (int cth = 0; cth < 2; ++cth)
#pragma unroll
      for (int q = 0; q < 4; ++q)
        br[cth][q] = bs[q * 256 + colbase + cth * 16 + fr];
  }
  float creg[2][2][4] = {};                       // [i][cth][r]
  u32* myflag = (p2 ? f2 : f1) + bb;

#pragma unroll 1
  for (int s = 0; s < 119; ++s) {
    // ---- X gate-addend fragment prefetch (normal cached loads; static data) ----
    const u16* Xb = nullptr;
    if (!p2) { if (s < 80) Xb = X1f + (size_t)s * XSTR; }
    else     { if (s >= 80) Xb = Xcf + (size_t)(s - 80) * XSTR; }
    int4 gav[8];
    if (Xb) {
      const int4* xp = (const int4*)(Xb + (((size_t)rg2 * 8 + cs8) * 64 + lane) * 64);
#pragma unroll
      for (int v = 0; v < 8; ++v) gav[v] = xp[v];
    }
    // ---- watermark poll (lanes 0..15, read-only sc1 loads; overlaps X prefetch) ----
    if (p2 || s > 0) {
      const u32 tA = p2 ? (u32)(s + 1) : (u32)s;
      const u32 tB = (u32)s;
      const u32* fB = p2 ? f2 : f1;
      while (true) {
        bool ok = true;
        if (lane < 8)
          ok = __hip_atomic_load(&f1[rg2 * 8 + lane], __ATOMIC_RELAXED,
                                 __HIP_MEMORY_SCOPE_AGENT) >= tA;
        else if (lane < 16)
          ok = __hip_atomic_load(&fB[rg2 * 8 + (lane - 8)], __ATOMIC_RELAXED,
                                 __HIP_MEMORY_SCOPE_AGENT) >= tB;
        if (__all(ok)) break;
        __builtin_amdgcn_s_sleep(1);
      }
    }
    // ---- A fragments (sc1, bypass stale L2) + MFMAs (B fragments streamed from L2) ----
    f4v acc[2][8] = {};
    const u16* h1s = h1hist + (size_t)(p2 ? s + 1 : s) * HSTR;
    const u16* h2s = h2hist + (size_t)s * HSTR;
    const int nkh = p2 ? 2 : 1;
#pragma unroll 1
    for (int kh = 0; kh < nkh; ++kh) {
      const u16* hbase = (kh == 0) ? h1s : h2s;
      s8v a[2][8];
#pragma unroll
      for (int i = 0; i < 2; ++i) {
        const u16* arow = hbase + (size_t)(rowbase + i * 16 + fr) * 256 + rq * 8;
#pragma unroll
        for (int k8 = 0; k8 < 8; ++k8) {
          const u64* src = (const u64*)(arow + k8 * 32);
          union { u64 q[2]; s8v v; } u;
          u.q[0] = __hip_atomic_load(src,     __ATOMIC_RELAXED, __HIP_MEMORY_SCOPE_AGENT);
          u.q[1] = __hip_atomic_load(src + 1, __ATOMIC_RELAXED, __HIP_MEMORY_SCOPE_AGENT);
          a[i][k8] = u.v;
        }
      }
#pragma unroll
      for (int k8 = 0; k8 < 8; ++k8) {
        const int kk = kh * 8 + k8;
        const int4* wb = (const int4*)Wf + ((size_t)(cs8 * 8) * KK + kk) * 64 + lane;
        s8v bf[8];
#pragma unroll
        for (int ct = 0; ct < 8; ++ct)
          bf[ct] = *(const s8v*)(wb + (size_t)ct * KK * 64);
#pragma unroll
        for (int ct = 0; ct < 8; ++ct) {
          acc[0][ct] = __builtin_amdgcn_mfma_f32_16x16x32_bf16(a[0][k8], bf[ct], acc[0][ct], 0, 0, 0);
          acc[1][ct] = __builtin_amdgcn_mfma_f32_16x16x32_bf16(a[1][k8], bf[ct], acc[1][ct], 0, 0, 0);
        }
      }
    }
    // ---- cell update + h store (paired bf16 -> one u32 sc1 store per even lane) ----
    u16* hws = (p2 ? h2hist : h1hist) + (size_t)(s + 1) * HSTR;
    const u32* gw = (const u32*)gav;
#pragma unroll
    for (int i = 0; i < 2; ++i)
#pragma unroll
      for (int cth = 0; cth < 2; ++cth)
#pragma unroll
        for (int r = 0; r < 4; ++r) {
          float g[4];
#pragma unroll
          for (int q = 0; q < 4; ++q) {
            float add;
            if (Xb) {
              const int e = ((i * 2 + cth) * 4 + q) * 4 + r;
              add = b2f((u16)(gw[e >> 1] >> ((e & 1) * 16)));
            } else add = br[cth][q];
            g[q] = acc[i][q * 2 + cth][r] + add;
          }
          float cn = sigm(g[1]) * creg[i][cth][r] + sigm(g[0]) * tanh_f(g[2]);
          float h = sigm(g[3]) * tanh_f(cn);
          creg[i][cth][r] = cn;
          u32 hb = f2b(h);
          u32 ob = (u32)__shfl_xor((int)hb, 1);
          if ((lane & 1) == 0) {
            const int row = rowbase + i * 16 + rq * 4 + r;
            const int col = colbase + cth * 16 + fr;
            __hip_atomic_store((u32*)(hws + (size_t)row * 256 + col), hb | (ob << 16),
                               __ATOMIC_RELAXED, __HIP_MEMORY_SCOPE_AGENT);
          }
        }
    asm volatile("s_waitcnt vmcnt(0)" ::: "memory");
    __hip_atomic_store(myflag, (u32)(s + 1), __ATOMIC_RELAXED, __HIP_MEMORY_SCOPE_AGENT);
  }
}

// ---------------- combine per-tile LSE partials -> per-row NLL -------------------------
__global__ __launch_bounds__(256) void nll_combine(const float* __restrict__ pm,
                                                   const float* __restrict__ ps,
                                                   const float* __restrict__ tgtlog,
                                                   float* __restrict__ rowloss) {
  int row = blockIdx.x * 256 + threadIdx.x;
  if (row >= 9984) return;
  const float* pmr = pm + (size_t)row * 48;
  const float* psr = ps + (size_t)row * 48;
  float M = -1e30f;
#pragma unroll
  for (int t = 0; t < 48; ++t) M = fmaxf(M, pmr[t]);
  float S = 0.f;
#pragma unroll
  for (int t = 0; t < 48; ++t) S += psr[t] * __expf(pmr[t] - M);
  rowloss[row] = M + __logf(S) - tgtlog[row];
}

__global__ __launch_bounds__(256) void final_kernel(const float* __restrict__ rowloss,
                                                    float* __restrict__ out) {
  float s = 0.f;
  for (int n = threadIdx.x; n < 9984; n += 256) s += rowloss[n];
#pragma unroll
  for (int o = 1; o < 64; o <<= 1) s += __shfl_xor(s, o);
  __shared__ float sr[4];
  if ((threadIdx.x & 63) == 0) sr[threadIdx.x >> 6] = s;
  __syncthreads();
  if (threadIdx.x == 0) out[0] = (sr[0] + sr[1] + sr[2] + sr[3]) * (1.f / 256.f);
}

// ---------------------------------------------------------------------------------------
extern "C" void kernel_launch(void* const* d_in, const int* in_sizes, int n_in,
                              void* d_out, int out_size, void* d_ws, size_t ws_size,
                              hipStream_t stream) {
  const float* feat    = (const float*)d_in[0];
  const float* caption = (const float*)d_in[1];
  const float* coh     = (const float*)d_in[2];
  const float* W_ih1   = (const float*)d_in[3];
  const float* W_hh1   = (const float*)d_in[4];
  const float* b_ih1   = (const float*)d_in[5];
  const float* b_hh1   = (const float*)d_in[6];
  const float* W_ih2   = (const float*)d_in[7];
  const float* W_hh2   = (const float*)d_in[8];
  const float* b_ih2   = (const float*)d_in[9];
  const float* b_hh2   = (const float*)d_in[10];
  const float* W_out   = (const float*)d_in[11];
  const float* b_out   = (const float*)d_in[12];

  char* p = (char*)d_ws;
  auto take = [&](size_t bytes) { char* r = p; p += (bytes + 255) & ~(size_t)255; return r; };
  u16* X1f    = (u16*)take(80ull * XSTR * 2);          // 41.9 MB fragment layout
  u16* Xcf    = (u16*)take(40ull * XSTR * 2);          // 21.0 MB
  u16* Wih1b  = (u16*)take(1024ull * 4096 * 2);
  u16* Wih2ab = (u16*)take(1024ull * 256 * 2);
  u16* Woutb  = (u16*)take((size_t)VOCP * 256 * 2);
  u16* Wf1    = (u16*)take(8ull * 8 * 8 * 64 * 8 * 2);    // 512 KB
  u16* Wf2    = (u16*)take(8ull * 8 * 16 * 64 * 8 * 2);   // 1 MB
  u16* h1hist = (u16*)take(120ull * HSTR * 2);         // 15.7 MB
  u16* h2hist = (u16*)take(120ull * HSTR * 2);         // 15.7 MB (slots 81..119 = H2dec)
  float* b1sum = (float*)take(1024 * 4);
  float* b2sum = (float*)take(1024 * 4);
  float* boutp = (float*)take(VOCP * 4);
  int*   tgt   = (int*)take(9984 * 4);
  float* tgtlog = (float*)take(9984 * 4);
  float* pm    = (float*)take(9984ull * 48 * 4);
  float* ps    = (float*)take(9984ull * 48 * 4);
  float* rowloss = (float*)take(9984 * 4);
  u32* f1      = (u32*)take(256);                      // 64 flags (contiguous with f2)
  u32* f2      = (u32*)take(256);
  // union region: {featb chunk (83.9 MB) + capb (5.2 MB)} only used before recurrence
  char* uni = p;
  u16* featb = (u16*)uni;
  u16* capb  = (u16*)(uni + 10240ull * 4096 * 2);

  // zero h slot 0 (both histories) and the watermark flags
  hipMemsetAsync(h1hist, 0, HSTR * 2, stream);
  hipMemsetAsync(h2hist, 0, HSTR * 2, stream);
  hipMemsetAsync(f1, 0, 512, stream);

  bias_setup<<<dim3(24), dim3(256), 0, stream>>>(b_ih1, b_hh1, b_ih2, b_hh2, b_out,
                                                 b1sum, b2sum, boutp);
  auto pack = [&](u16* dst, int dld, int doff, const float* src, int sld, int soff,
                  int Wc, int R, int Rs) {
    int tot = Wc * R;
    pack_bf16<<<dim3((tot + 255) / 256), dim3(256), 0, stream>>>(dst, dld, doff, src, sld, soff,
                                                                 Wc, R, Rs);
  };
  pack(Wih1b, 4096, 0, W_ih1, 4096, 0, 4096, 1024, 1024);
  pack(Wih2ab, 256, 0, W_ih2, 512, 0, 256, 1024, 1024);     // W_ih2[:, :256]
  pack(Woutb, 256, 0, W_out, 256, 0, 256, VOCP, VOC);       // zero-padded rows
  wfrag_pack<8><<<dim3(128), dim3(256), 0, stream>>>(Wf1, W_hh1, nullptr);
  wfrag_pack<16><<<dim3(256), dim3(256), 0, stream>>>(Wf2, W_ih2, W_hh2);

  argmax_kernel<<<dim3(39 * 256), dim3(256), 0, stream>>>(coh, tgt);

  // caption -> bf16, Xcf = capb @ Wih2a^T + b2sum   (fragment epilogue)
  conv_f2b<<<dim3(2048), dim3(256), 0, stream>>>(caption, capb, 10240L * 256);
  gemm_bb<1><<<dim3(80, 4), dim3(256), 0, stream>>>(capb, Wih2ab, b2sum, Xcf,
                                                    nullptr, nullptr, nullptr, 256, 0);

  // feat -> bf16 (2 chunks), X1f = featb @ Wih1^T + b1sum   (fragment epilogue)
  for (int c = 0; c < 2; ++c) {
    conv_f2b<<<dim3(2048), dim3(256), 0, stream>>>(feat + (size_t)c * 10240 * 4096, featb,
                                                   10240L * 4096);
    gemm_bb<0><<<dim3(80, 4), dim3(256), 0, stream>>>(featb, Wih1b, b1sum, X1f,
                                                      nullptr, nullptr, nullptr, 4096,
                                                      c * 10240);
  }

  // whole 119-step double-LSTM recurrence: 128 independent waves, watermark pipeline
  recur_kernel<<<dim3(128), dim3(64), 0, stream>>>(X1f, Xcf, b1sum, b2sum,
                                                   Wf1, Wf2, h1hist, h2hist, f1, f2);

  // logits GEMM with fused per-tile LSE partials + target-logit extraction
  gemm_bb<2><<<dim3(78, 24), dim3(256), 0, stream>>>(h2hist + 81ull * HSTR, Woutb, boutp, pm,
                                                     ps, tgtlog, tgt, 256, 0);
  nll_combine<<<dim3(39), dim3(256), 0, stream>>>(pm, ps, tgtlog, rowloss);
  final_kernel<<<dim3(1), dim3(256), 0, stream>>>(rowloss, (float*)d_out);
}

// Round 7
// 3271.106 us; speedup vs baseline: 1.2361x; 1.2361x over previous
//
#include <hip/hip_runtime.h>

// Net_39135742001869: S2VT video-caption LSTM (enc 80 + dec 39 steps), bf16 MFMA.
// R7: R6's 3-stage pipelined recurrence (A=LSTM1, B=h1@Wih2b, C=LSTM2) with ALL manual
// vmcnt counting removed — compiler-managed waits (atomic u64 h/y loads, plain X loads).

typedef unsigned short u16;
typedef unsigned int u32;
typedef unsigned long long u64;
typedef __attribute__((ext_vector_type(8))) short s8v;   // 8 x bf16
typedef __attribute__((ext_vector_type(4))) float f4v;   // MFMA accumulator

#define VOC   6000
#define VOCP  6144
#define HSTR  65536       // 256*256 h-history slot stride (elems)
#define XSTR  262144      // 4rg*4cs*4w*64lane*64elem fragment step stride (elems)

__device__ __forceinline__ u16 f2b(float f) {
  unsigned u = __float_as_uint(f);
  return (u16)((u + 0x7fffu + ((u >> 16) & 1u)) >> 16);   // RNE f32->bf16
}
__device__ __forceinline__ float b2f(u16 u) { return __uint_as_float(((unsigned)u) << 16); }
__device__ __forceinline__ float sigm(float x) { return 1.f / (1.f + __expf(-x)); }
__device__ __forceinline__ float tanh_f(float x) {
  float e = __expf(-2.f * fabsf(x));
  float t = (1.f - e) / (1.f + e);
  return x >= 0.f ? t : -t;
}
__device__ __forceinline__ u32 geti4(const int4& v, int c) {
  return c == 0 ? (u32)v.x : c == 1 ? (u32)v.y : c == 2 ? (u32)v.z : (u32)v.w;
}
__device__ __forceinline__ s8v asv(const int4& v) { return __builtin_bit_cast(s8v, v); }
// 16B coherent (agent-relaxed atomic) load as MFMA fragment — compiler-managed waits
__device__ __forceinline__ s8v ld16a(const u16* p) {
  union { u64 q[2]; s8v v; } u;
  const u64* s = (const u64*)p;
  u.q[0] = __hip_atomic_load(s,     __ATOMIC_RELAXED, __HIP_MEMORY_SCOPE_AGENT);
  u.q[1] = __hip_atomic_load(s + 1, __ATOMIC_RELAXED, __HIP_MEMORY_SCOPE_AGENT);
  return u.v;
}

// ---------------- f32 -> bf16 row-permuted conversion: dst[tl*256+b] = src[b*T+toff+tl]
__global__ __launch_bounds__(256) void conv_tr(const float* __restrict__ src,
                                               u16* __restrict__ dst, int T, int D, int toff) {
  const int tl = blockIdx.x >> 8, b = blockIdx.x & 255;
  const float* s = src + ((size_t)b * T + toff + tl) * D;
  u16* d = dst + (size_t)blockIdx.x * D;
  for (int i = threadIdx.x * 8; i < D; i += 2048) {
    float4 a = *(const float4*)(s + i);
    float4 c = *(const float4*)(s + i + 4);
    unsigned w0 = (unsigned)f2b(a.x) | ((unsigned)f2b(a.y) << 16);
    unsigned w1 = (unsigned)f2b(a.z) | ((unsigned)f2b(a.w) << 16);
    unsigned w2 = (unsigned)f2b(c.x) | ((unsigned)f2b(c.y) << 16);
    unsigned w3 = (unsigned)f2b(c.z) | ((unsigned)f2b(c.w) << 16);
    *(int4*)(d + i) = make_int4((int)w0, (int)w1, (int)w2, (int)w3);
  }
}

// ---------------- weight pack (f32 -> bf16) --------------------------------------------
__global__ void pack_bf16(u16* __restrict__ dst, int dld, int doff,
                          const float* __restrict__ src, int sld, int soff,
                          int Wc, int R, int Rsrc) {
  int i = blockIdx.x * 256 + threadIdx.x;
  if (i >= Wc * R) return;
  int r = i / Wc, c = i - r * Wc;
  float v = (r < Rsrc) ? src[(size_t)r * sld + soff + c] : 0.f;
  dst[(size_t)r * dld + doff + c] = f2b(v);
}

// ---------------- recurrence weight -> per-wave MFMA fragments -------------------------
// dst[((cs*4+w)*4+nt)*8+kk][lane][8].  MODE 0/2: g = nt*256+cs*64+w*16+(lane&15), k col.
// MODE 1 (Wih2b): g = cs*256+w*64+nt*16+(lane&15), src col 256+k of W_ih2 (ld 512).
template <int MODE>
__global__ __launch_bounds__(256) void wfrag_pack(u16* __restrict__ dst,
                                                  const float* __restrict__ src) {
  int idx = blockIdx.x * 256 + threadIdx.x;
  if (idx >= 32768) return;
  int lane = idx & 63;
  int t = idx >> 6;
  int kk = t & 7; t >>= 3;
  int nt = t & 3; t >>= 2;
  int w = t & 3, cs = t >> 2;
  int g = (MODE == 1) ? cs * 256 + w * 64 + nt * 16 + (lane & 15)
                      : nt * 256 + cs * 64 + w * 16 + (lane & 15);
  int k0 = kk * 32 + (lane >> 4) * 8;
  u16 out[8];
#pragma unroll
  for (int e = 0; e < 8; ++e) {
    float v = (MODE == 1) ? src[(size_t)g * 512 + 256 + k0 + e]
                          : src[(size_t)g * 256 + k0 + e];
    out[e] = f2b(v);
  }
  *(int4*)(dst + (size_t)idx * 8) = *(const int4*)out;
}

__global__ void bias_setup(const float* __restrict__ bi1, const float* __restrict__ bh1,
                           const float* __restrict__ bi2, const float* __restrict__ bh2,
                           const float* __restrict__ bo,
                           float* __restrict__ b1s, float* __restrict__ b2s,
                           float* __restrict__ bop) {
  int i = blockIdx.x * 256 + threadIdx.x;
  if (i < 1024) { b1s[i] = bi1[i] + bh1[i]; b2s[i] = bi2[i] + bh2[i]; }
  if (i < VOCP) bop[i] = (i < VOC) ? bo[i] : -1e30f;
}

// ---------------- targets = argmax(caption_one_hot[b, d+1, :]) -------------------------
__global__ __launch_bounds__(256) void argmax_kernel(const float* __restrict__ coh,
                                                     int* __restrict__ tgt) {
  const int d = blockIdx.x >> 8;
  const int b = blockIdx.x & 255;
  const float4* row = (const float4*)(coh + ((size_t)b * 40 + (d + 1)) * VOC);
  float best = -3.4e38f; int bi = 0;
  for (int v = threadIdx.x; v < VOC / 4; v += 256) {
    float4 x = row[v];
    float vals[4] = {x.x, x.y, x.z, x.w};
#pragma unroll
    for (int j = 0; j < 4; ++j)
      if (vals[j] > best) { best = vals[j]; bi = v * 4 + j; }
  }
#pragma unroll
  for (int o = 1; o < 64; o <<= 1) {
    float ov = __shfl_xor(best, o);
    int   oi = __shfl_xor(bi, o);
    if (ov > best || (ov == best && oi < bi)) { best = ov; bi = oi; }
  }
  __shared__ float sv[4]; __shared__ int si[4];
  if ((threadIdx.x & 63) == 0) { sv[threadIdx.x >> 6] = best; si[threadIdx.x >> 6] = bi; }
  __syncthreads();
  if (threadIdx.x == 0) {
    for (int i = 1; i < 4; ++i)
      if (sv[i] > best || (sv[i] == best && si[i] < bi)) { best = sv[i]; bi = si[i]; }
    tgt[blockIdx.x] = bi;   // [d][b]
  }
}

// ---------------- GEMM: acc = A_bf16[M][K] * Bw_bf16[N][K]^T (+bias) -------------------
// grid (M/128, N/256). MODE 0: fragment epilogue (A rows time-major t*256+b);
// MODE 2: fused NLL partials. XCD-bijective swizzle on the m-tile index.
template <int MODE>
__global__ __launch_bounds__(256) void gemm_bb(
    const u16* __restrict__ A, const u16* __restrict__ Bw,
    const float* __restrict__ bias, void* __restrict__ out0,
    float* __restrict__ ps, float* __restrict__ tgtlog, const int* __restrict__ tgt,
    int K, int moff)
{
  const int nx = gridDim.x;
  const int qq = nx >> 3, rm = nx & 7;
  const int xcd = (int)blockIdx.x & 7, pos = (int)blockIdx.x >> 3;
  const int mt = (xcd < rm) ? (xcd * (qq + 1) + pos)
                            : (rm * (qq + 1) + (xcd - rm) * qq + pos);
  const int m0 = mt * 128;
  const int n0 = blockIdx.y * 256;
  const int tid = threadIdx.x;
  const int lane = tid & 63;
  const int wid = tid >> 6;
  const int wm = wid >> 1, wn = wid & 1;
  const int fr = lane & 15;
  const int fk = (lane >> 4) * 8;
  const int rq = lane >> 4;

  __shared__ u16 As[128][72];
  __shared__ u16 Bs[256][72];
  f4v acc[4][8] = {};

  const int ar = tid >> 1, ac = (tid & 1) * 32;
  int4 av[4], bv[8];
  {
    const u16* ap = A + (size_t)(m0 + ar) * K + ac;
    const u16* bp = Bw + (size_t)(n0 + tid) * K;
#pragma unroll
    for (int v = 0; v < 4; ++v) av[v] = *(const int4*)(ap + v * 8);
#pragma unroll
    for (int v = 0; v < 8; ++v) bv[v] = *(const int4*)(bp + v * 8);
  }
#pragma unroll 1
  for (int k0 = 0; k0 < K; k0 += 64) {
    __syncthreads();
#pragma unroll
    for (int v = 0; v < 4; ++v) *(int4*)&As[ar][ac + v * 8] = av[v];
#pragma unroll
    for (int v = 0; v < 8; ++v) *(int4*)&Bs[tid][v * 8] = bv[v];
    __syncthreads();
    if (k0 + 64 < K) {
      const u16* ap = A + (size_t)(m0 + ar) * K + k0 + 64 + ac;
      const u16* bp = Bw + (size_t)(n0 + tid) * K + k0 + 64;
#pragma unroll
      for (int v = 0; v < 4; ++v) av[v] = *(const int4*)(ap + v * 8);
#pragma unroll
      for (int v = 0; v < 8; ++v) bv[v] = *(const int4*)(bp + v * 8);
    }
#pragma unroll
    for (int ks = 0; ks < 2; ++ks) {
      const int kb = ks * 32 + fk;
      s8v a[4], b[8];
#pragma unroll
      for (int i = 0; i < 4; ++i) a[i] = *(const s8v*)&As[wm * 64 + i * 16 + fr][kb];
#pragma unroll
      for (int j = 0; j < 8; ++j) b[j] = *(const s8v*)&Bs[wn * 128 + j * 16 + fr][kb];
#pragma unroll
      for (int i = 0; i < 4; ++i)
#pragma unroll
        for (int j = 0; j < 8; ++j)
          acc[i][j] = __builtin_amdgcn_mfma_f32_16x16x32_bf16(a[i], b[j], acc[i][j], 0, 0, 0);
    }
  }

  float bz[8];
#pragma unroll
  for (int j = 0; j < 8; ++j) bz[j] = bias[n0 + wn * 128 + j * 16 + fr];

  if (MODE == 2) {
    const int tile = blockIdx.y * 2 + wn;
    float* pm = (float*)out0;
#pragma unroll
    for (int i = 0; i < 4; ++i) {
#pragma unroll
      for (int r = 0; r < 4; ++r) {
        const int row = m0 + wm * 64 + i * 16 + rq * 4 + r;
        const int tg = tgt[row];
        float vj[8]; float m = -1e30f;
#pragma unroll
        for (int j = 0; j < 8; ++j) {
          const int n = n0 + wn * 128 + j * 16 + fr;
          float v = acc[i][j][r] + bz[j];
          vj[j] = v;
          m = fmaxf(m, v);
          if (n == tg) tgtlog[row] = v;
        }
#pragma unroll
        for (int o = 1; o < 16; o <<= 1) m = fmaxf(m, __shfl_xor(m, o));
        float s = 0.f;
#pragma unroll
        for (int j = 0; j < 8; ++j) s += __expf(vj[j] - m);
#pragma unroll
        for (int o = 1; o < 16; o <<= 1) s += __shfl_xor(s, o);
        if (fr == 0) { pm[(size_t)row * 48 + tile] = m; ps[(size_t)row * 48 + tile] = s; }
      }
    }
  } else {
    // fragment epilogue: rows are time-major (mb = tt*256 + bat); pack 4 r's -> one u64
    u16* X = (u16*)out0;
#pragma unroll
    for (int i = 0; i < 4; ++i) {
      const int mb = moff + m0 + wm * 64 + i * 16 + rq * 4;   // r = 0 row
      const int tt = mb >> 8, bat = mb & 255;
      const int rgf = bat >> 6, iff = (bat >> 4) & 3;
#pragma unroll
      for (int j = 0; j < 8; ++j) {
        const int n = n0 + wn * 128 + j * 16 + fr;
        const int q = n >> 8, rest = n & 255;
        const int csf = rest >> 6, wf = (rest >> 4) & 3;
        const size_t sblk = ((size_t)(tt * 4 + rgf) * 4 + csf) * 4 + wf;
        u64 pk = 0;
#pragma unroll
        for (int r = 0; r < 4; ++r)
          pk |= (u64)f2b(acc[i][j][r] + bz[j]) << (r * 16);
        *(u64*)(X + (sblk * 64 + (size_t)(rq * 16 + fr)) * 64 + (iff * 4 + q) * 4) = pk;
      }
    }
  }
}

// ---------------- 3-stage pipelined recurrence -----------------------------------------
// 48 blocks x 256 thr. Stage = bid>>4: 0=A (LSTM1), 1=B (y=h1@Wih2b^T), 2=C (LSTM2).
// Sub-block (rg 0..3, cs 0..3); wave w 0..3. A/C: wave owns rows rg*64..+64 x cols
// cs*64+w*16..+16 (all 4 gates). B: wave owns y-cols cs*256+w*64..+64.
// Histories h1hist/h2hist[120][256][256]; slot s+1 = h(s); slot 0 zeroed.
// yfrag[s][rg][csC][wC][lane][64]: C's gate addend, written by B in C's fragment order.
// Publish: atomic data stores -> s_waitcnt vmcnt(0) -> relaxed agent flag store
// (R4/R5-proven protocol; NO manual counted vmcnt anywhere).
__global__ __launch_bounds__(256, 1) void recur_kernel(
    const u16* __restrict__ X1f, const u16* __restrict__ Xcf,
    const float* __restrict__ b1sum, const float* __restrict__ b2sum,
    const u16* __restrict__ WfA, const u16* __restrict__ WfB, const u16* __restrict__ WfC,
    u16* __restrict__ h1hist, u16* __restrict__ h2hist, u16* __restrict__ yfrag,
    u32* __restrict__ flags)
{
  const int tid = threadIdx.x, lane = tid & 63, w = tid >> 6;
  const int stage = blockIdx.x >> 4, sub = blockIdx.x & 15;
  const int rg = sub >> 2, cs = sub & 3;
  const int fr = lane & 15, rq = lane >> 4;
  u32* fA = flags; u32* fY = flags + 64; u32* fC = flags + 128;

  // one-time: 32 weight fragments -> VGPRs (128 regs), plain cached loads
  const u16* Wf = stage == 0 ? WfA : stage == 1 ? WfB : WfC;
  int4 wv[4][8];
#pragma unroll
  for (int nt = 0; nt < 4; ++nt)
#pragma unroll
    for (int kk = 0; kk < 8; ++kk)
      wv[nt][kk] = *(const int4*)(Wf +
                   (((size_t)((cs * 4 + w) * 32 + nt * 8 + kk)) * 64 + lane) * 8);

  float br[4];
  {
    const float* bs = (stage == 2) ? b2sum : b1sum;
#pragma unroll
    for (int q = 0; q < 4; ++q) br[q] = bs[q * 256 + cs * 64 + w * 16 + fr];
  }
  u32* myflag = flags + stage * 64 + rg * 16 + cs * 4 + w;
  float creg[4][4] = {};

  if (stage == 0) {                      // ================= A: LSTM1 =================
#pragma unroll 1
    for (int s = 0; s < 119; ++s) {
      if (s > 0) {
        while (true) {
          bool ok = true;
          if (lane < 16)
            ok = __hip_atomic_load(&fA[rg * 16 + lane], __ATOMIC_RELAXED,
                                   __HIP_MEMORY_SCOPE_AGENT) >= (u32)s;
          if (__all(ok)) break;
          __builtin_amdgcn_s_sleep(1);
        }
        __builtin_amdgcn_sched_barrier(0);
      }
      s8v a[4][8];
      const u16* hb = h1hist + (size_t)s * HSTR;
#pragma unroll
      for (int i = 0; i < 4; ++i) {
        const u16* ap = hb + (size_t)(rg * 64 + i * 16 + fr) * 256 + rq * 8;
#pragma unroll
        for (int kk = 0; kk < 8; ++kk) a[i][kk] = ld16a(ap + kk * 32);
      }
      int4 xv[8];
      const u16* xb = (s < 80)
          ? X1f + (((size_t)(((s * 4 + rg) * 4 + cs) * 4 + w)) * 64 + lane) * 64
          : X1f + (size_t)lane * 64;    // dummy (discarded)
#pragma unroll
      for (int v = 0; v < 8; ++v) xv[v] = *(const int4*)(xb + v * 8);
      f4v acc[4][4] = {};
#pragma unroll
      for (int i = 0; i < 4; ++i)
#pragma unroll
        for (int kk = 0; kk < 8; ++kk)
#pragma unroll
          for (int q = 0; q < 4; ++q)
            acc[i][q] = __builtin_amdgcn_mfma_f32_16x16x32_bf16(a[i][kk], asv(wv[q][kk]),
                                                                acc[i][q], 0, 0, 0);
      u16* hw = h1hist + (size_t)(s + 1) * HSTR;
#pragma unroll
      for (int i = 0; i < 4; ++i)
#pragma unroll
        for (int r = 0; r < 4; ++r) {
          float g[4];
#pragma unroll
          for (int q = 0; q < 4; ++q) {
            const int e = (i * 4 + q) * 4 + r;
            float xe = b2f((u16)(geti4(xv[e >> 3], (e >> 1) & 3) >> ((e & 1) * 16)));
            g[q] = acc[i][q][r] + (s < 80 ? xe : br[q]);
          }
          float cn = sigm(g[1]) * creg[i][r] + sigm(g[0]) * tanh_f(g[2]);
          float h = sigm(g[3]) * tanh_f(cn);
          creg[i][r] = cn;
          u32 hbv = f2b(h);
          u32 ob = (u32)__shfl_xor((int)hbv, 1);
          if (!(fr & 1))
            __hip_atomic_store(
                (u32*)(hw + (size_t)(rg * 64 + i * 16 + rq * 4 + r) * 256 + cs * 64 + w * 16 + fr),
                hbv | (ob << 16), __ATOMIC_RELAXED, __HIP_MEMORY_SCOPE_AGENT);
        }
      asm volatile("s_waitcnt vmcnt(0)" ::: "memory");
      if (lane == 0)
        __hip_atomic_store(myflag, (u32)(s + 1), __ATOMIC_RELAXED, __HIP_MEMORY_SCOPE_AGENT);
    }
  } else if (stage == 1) {               // ================= B: y = h1 @ Wih2b^T ======
#pragma unroll 1
    for (int s = 0; s < 119; ++s) {
      while (true) {
        bool ok = true;
        if (lane < 16)
          ok = __hip_atomic_load(&fA[rg * 16 + lane], __ATOMIC_RELAXED,
                                 __HIP_MEMORY_SCOPE_AGENT) >= (u32)(s + 1);
        if (__all(ok)) break;
        __builtin_amdgcn_s_sleep(1);
      }
      __builtin_amdgcn_sched_barrier(0);
      s8v a[4][8];
      const u16* hb = h1hist + (size_t)(s + 1) * HSTR;
#pragma unroll
      for (int i = 0; i < 4; ++i) {
        const u16* ap = hb + (size_t)(rg * 64 + i * 16 + fr) * 256 + rq * 8;
#pragma unroll
        for (int kk = 0; kk < 8; ++kk) a[i][kk] = ld16a(ap + kk * 32);
      }
      f4v acc[4][4] = {};
#pragma unroll
      for (int i = 0; i < 4; ++i)
#pragma unroll
        for (int kk = 0; kk < 8; ++kk)
#pragma unroll
          for (int j = 0; j < 4; ++j)
            acc[i][j] = __builtin_amdgcn_mfma_f32_16x16x32_bf16(a[i][kk], asv(wv[j][kk]),
                                                                acc[i][j], 0, 0, 0);
      // write y in C's fragment order: yslot(s, rg, csC=w, wC=j), elem (i*4+csB)*4+r
#pragma unroll
      for (int i = 0; i < 4; ++i)
#pragma unroll
        for (int j = 0; j < 4; ++j) {
          u64 pk = 0;
#pragma unroll
          for (int r = 0; r < 4; ++r) pk |= (u64)f2b(acc[i][j][r]) << (r * 16);
          u16* dst = yfrag + (((size_t)(((s * 4 + rg) * 4 + w) * 4 + j)) * 64 + lane) * 64 +
                     (i * 4 + cs) * 4;
          __hip_atomic_store((u64*)dst, pk, __ATOMIC_RELAXED, __HIP_MEMORY_SCOPE_AGENT);
        }
      asm volatile("s_waitcnt vmcnt(0)" ::: "memory");
      if (lane == 0)
        __hip_atomic_store(myflag, (u32)(s + 1), __ATOMIC_RELAXED, __HIP_MEMORY_SCOPE_AGENT);
    }
  } else {                               // ================= C: LSTM2 (K=256) =========
#pragma unroll 1
    for (int s = 0; s < 119; ++s) {
      int4 xv[8];
      const u16* xb = (s >= 80)
          ? Xcf + (((size_t)((((s - 80) * 4 + rg) * 4 + cs) * 4 + w)) * 64 + lane) * 64
          : Xcf + (size_t)lane * 64;    // dummy
#pragma unroll
      for (int v = 0; v < 8; ++v) xv[v] = *(const int4*)(xb + v * 8);
      {
        const u32 t1 = (u32)(s + 1), t2 = (u32)s;
        while (true) {
          bool ok = true;
          if (lane < 16)
            ok = __hip_atomic_load(&fY[rg * 16 + lane], __ATOMIC_RELAXED,
                                   __HIP_MEMORY_SCOPE_AGENT) >= t1;
          else if (lane < 32 && s > 0)
            ok = __hip_atomic_load(&fC[rg * 16 + (lane - 16)], __ATOMIC_RELAXED,
                                   __HIP_MEMORY_SCOPE_AGENT) >= t2;
          if (__all(ok)) break;
          __builtin_amdgcn_s_sleep(1);
        }
        __builtin_amdgcn_sched_barrier(0);
      }
      s8v a[4][8];
      const u16* hb = h2hist + (size_t)s * HSTR;
#pragma unroll
      for (int i = 0; i < 4; ++i) {
        const u16* ap = hb + (size_t)(rg * 64 + i * 16 + fr) * 256 + rq * 8;
#pragma unroll
        for (int kk = 0; kk < 8; ++kk) a[i][kk] = ld16a(ap + kk * 32);
      }
      u64 yq[16];
      {
        const u64* yb = (const u64*)(yfrag +
            (((size_t)(((s * 4 + rg) * 4 + cs) * 4 + w)) * 64 + lane) * 64);
#pragma unroll
        for (int k = 0; k < 16; ++k)
          yq[k] = __hip_atomic_load(yb + k, __ATOMIC_RELAXED, __HIP_MEMORY_SCOPE_AGENT);
      }
      f4v acc[4][4] = {};
#pragma unroll
      for (int i = 0; i < 4; ++i)
#pragma unroll
        for (int kk = 0; kk < 8; ++kk)
#pragma unroll
          for (int q = 0; q < 4; ++q)
            acc[i][q] = __builtin_amdgcn_mfma_f32_16x16x32_bf16(a[i][kk], asv(wv[q][kk]),
                                                                acc[i][q], 0, 0, 0);
      u16* hw = h2hist + (size_t)(s + 1) * HSTR;
#pragma unroll
      for (int i = 0; i < 4; ++i)
#pragma unroll
        for (int r = 0; r < 4; ++r) {
          float g[4];
#pragma unroll
          for (int q = 0; q < 4; ++q) {
            const int e = (i * 4 + q) * 4 + r;
            float ye = b2f((u16)(yq[e >> 2] >> ((e & 3) * 16)));
            float xe = b2f((u16)(geti4(xv[e >> 3], (e >> 1) & 3) >> ((e & 1) * 16)));
            g[q] = acc[i][q][r] + ye + (s >= 80 ? xe : br[q]);
          }
          float cn = sigm(g[1]) * creg[i][r] + sigm(g[0]) * tanh_f(g[2]);
          float h = sigm(g[3]) * tanh_f(cn);
          creg[i][r] = cn;
          u32 hbv = f2b(h);
          u32 ob = (u32)__shfl_xor((int)hbv, 1);
          if (!(fr & 1))
            __hip_atomic_store(
                (u32*)(hw + (size_t)(rg * 64 + i * 16 + rq * 4 + r) * 256 + cs * 64 + w * 16 + fr),
                hbv | (ob << 16), __ATOMIC_RELAXED, __HIP_MEMORY_SCOPE_AGENT);
        }
      asm volatile("s_waitcnt vmcnt(0)" ::: "memory");
      if (lane == 0)
        __hip_atomic_store(myflag, (u32)(s + 1), __ATOMIC_RELAXED, __HIP_MEMORY_SCOPE_AGENT);
    }
  }
}

// ---------------- combine per-tile LSE partials -> per-row NLL -------------------------
__global__ __launch_bounds__(256) void nll_combine(const float* __restrict__ pm,
                                                   const float* __restrict__ ps,
                                                   const float* __restrict__ tgtlog,
                                                   float* __restrict__ rowloss) {
  int row = blockIdx.x * 256 + threadIdx.x;
  if (row >= 9984) return;
  const float* pmr = pm + (size_t)row * 48;
  const float* psr = ps + (size_t)row * 48;
  float M = -1e30f;
#pragma unroll
  for (int t = 0; t < 48; ++t) M = fmaxf(M, pmr[t]);
  float S = 0.f;
#pragma unroll
  for (int t = 0; t < 48; ++t) S += psr[t] * __expf(pmr[t] - M);
  rowloss[row] = M + __logf(S) - tgtlog[row];
}

__global__ __launch_bounds__(256) void final_kernel(const float* __restrict__ rowloss,
                                                    float* __restrict__ out) {
  float s = 0.f;
  for (int n = threadIdx.x; n < 9984; n += 256) s += rowloss[n];
#pragma unroll
  for (int o = 1; o < 64; o <<= 1) s += __shfl_xor(s, o);
  __shared__ float sr[4];
  if ((threadIdx.x & 63) == 0) sr[threadIdx.x >> 6] = s;
  __syncthreads();
  if (threadIdx.x == 0) out[0] = (sr[0] + sr[1] + sr[2] + sr[3]) * (1.f / 256.f);
}

// ---------------------------------------------------------------------------------------
extern "C" void kernel_launch(void* const* d_in, const int* in_sizes, int n_in,
                              void* d_out, int out_size, void* d_ws, size_t ws_size,
                              hipStream_t stream) {
  const float* feat    = (const float*)d_in[0];
  const float* caption = (const float*)d_in[1];
  const float* coh     = (const float*)d_in[2];
  const float* W_ih1   = (const float*)d_in[3];
  const float* W_hh1   = (const float*)d_in[4];
  const float* b_ih1   = (const float*)d_in[5];
  const float* b_hh1   = (const float*)d_in[6];
  const float* W_ih2   = (const float*)d_in[7];
  const float* W_hh2   = (const float*)d_in[8];
  const float* b_ih2   = (const float*)d_in[9];
  const float* b_hh2   = (const float*)d_in[10];
  const float* W_out   = (const float*)d_in[11];
  const float* b_out   = (const float*)d_in[12];

  char* p = (char*)d_ws;
  auto take = [&](size_t bytes) { char* r = p; p += (bytes + 255) & ~(size_t)255; return r; };
  u16* X1f    = (u16*)take(80ull * XSTR * 2);          // 41.9 MB, fragment layout
  u16* Xcf    = (u16*)take(40ull * XSTR * 2);          // 21.0 MB
  u16* h1hist = (u16*)take(120ull * HSTR * 2);         // 15.7 MB
  u16* h2hist = (u16*)take(120ull * HSTR * 2);         // 15.7 MB (slots 81.. = H2dec)
  u16* Wih1b  = (u16*)take(1024ull * 4096 * 2);
  u16* Wih2ab = (u16*)take(1024ull * 256 * 2);
  u16* Woutb  = (u16*)take((size_t)VOCP * 256 * 2);
  u16* WfA    = (u16*)take(32768ull * 8 * 2);          // 512 KB each
  u16* WfB    = (u16*)take(32768ull * 8 * 2);
  u16* WfC    = (u16*)take(32768ull * 8 * 2);
  float* b1sum = (float*)take(1024 * 4);
  float* b2sum = (float*)take(1024 * 4);
  float* boutp = (float*)take(VOCP * 4);
  int*   tgt   = (int*)take(9984 * 4);
  float* tgtlog = (float*)take(9984 * 4);
  float* pm    = (float*)take(9984ull * 48 * 4);
  float* ps    = (float*)take(9984ull * 48 * 4);
  float* rowloss = (float*)take(9984 * 4);
  u32* flags   = (u32*)take(768);                      // fA|fY|fC  u32[3][64]
  // union region (84 MB): capT / featT chunk (pre-recurrence) then yfrag (recurrence)
  char* uni = take(10240ull * 4096 * 2);
  u16* capT  = (u16*)uni;            // 10240 x 256  (dead before featT written)
  u16* featT = (u16*)uni;            // 10240 x 4096, per chunk
  u16* yfrag = (u16*)uni;            // 119 * XSTR = 62.4 MB (recurrence only)

  hipMemsetAsync(h1hist, 0, HSTR * 2, stream);
  hipMemsetAsync(h2hist, 0, HSTR * 2, stream);
  hipMemsetAsync(flags, 0, 768, stream);

  bias_setup<<<dim3(24), dim3(256), 0, stream>>>(b_ih1, b_hh1, b_ih2, b_hh2, b_out,
                                                 b1sum, b2sum, boutp);
  auto pack = [&](u16* dst, int dld, int doff, const float* src, int sld, int soff,
                  int Wc, int R, int Rs) {
    int tot = Wc * R;
    pack_bf16<<<dim3((tot + 255) / 256), dim3(256), 0, stream>>>(dst, dld, doff, src, sld, soff,
                                                                 Wc, R, Rs);
  };
  pack(Wih1b, 4096, 0, W_ih1, 4096, 0, 4096, 1024, 1024);
  pack(Wih2ab, 256, 0, W_ih2, 512, 0, 256, 1024, 1024);     // W_ih2[:, :256]
  pack(Woutb, 256, 0, W_out, 256, 0, 256, VOCP, VOC);
  wfrag_pack<0><<<dim3(128), dim3(256), 0, stream>>>(WfA, W_hh1);
  wfrag_pack<1><<<dim3(128), dim3(256), 0, stream>>>(WfB, W_ih2);
  wfrag_pack<2><<<dim3(128), dim3(256), 0, stream>>>(WfC, W_hh2);

  argmax_kernel<<<dim3(39 * 256), dim3(256), 0, stream>>>(coh, tgt);

  // caption -> capT (time-major bf16) -> Xcf fragments (b2 folded)
  conv_tr<<<dim3(10240), dim3(256), 0, stream>>>(caption, capT, 40, 256, 0);
  gemm_bb<0><<<dim3(80, 4), dim3(256), 0, stream>>>(capT, Wih2ab, b2sum, Xcf,
                                                    nullptr, nullptr, nullptr, 256, 0);
  // feat -> featT (time-major bf16, 2 chunks) -> X1f fragments (b1 folded)
  for (int c = 0; c < 2; ++c) {
    conv_tr<<<dim3(10240), dim3(256), 0, stream>>>(feat, featT, 80, 4096, c * 40);
    gemm_bb<0><<<dim3(80, 4), dim3(256), 0, stream>>>(featT, Wih1b, b1sum, X1f,
                                                      nullptr, nullptr, nullptr, 4096,
                                                      c * 10240);
  }

  // whole 119-step recurrence: 48 blocks (A/B/C stages), watermark pipeline
  recur_kernel<<<dim3(48), dim3(256), 0, stream>>>(X1f, Xcf, b1sum, b2sum,
                                                   WfA, WfB, WfC,
                                                   h1hist, h2hist, yfrag, flags);

  // logits GEMM (A = h2 decode slots) with fused LSE partials + target logit
  gemm_bb<2><<<dim3(78, 24), dim3(256), 0, stream>>>(h2hist + 81ull * HSTR, Woutb, boutp, pm,
                                                     ps, tgtlog, tgt, 256, 0);
  nll_combine<<<dim3(39), dim3(256), 0, stream>>>(pm, ps, tgtlog, rowloss);
  final_kernel<<<dim3(1), dim3(256), 0, stream>>>(rowloss, (float*)d_out);
}

// Round 8
// 3244.226 us; speedup vs baseline: 1.2463x; 1.0083x over previous
//
#include <hip/hip_runtime.h>

// Net_39135742001869: S2VT video-caption LSTM (enc 80 + dec 39 steps), bf16 MFMA.
// R8: 3-stage recurrence (A=LSTM1, B=y-GEMM pipeline, C=LSTM2), LDS-resident swizzled
// weights (128KB/block), swapped-operand MFMA (u64 h-exchange), 4-flag dword polls.

typedef unsigned short u16;
typedef unsigned int u32;
typedef unsigned long long u64;
typedef __attribute__((ext_vector_type(8))) short s8v;   // 8 x bf16
typedef __attribute__((ext_vector_type(4))) float f4v;   // MFMA accumulator

#define VOC   6000
#define VOCP  6144
#define HSTR  65536       // 256*256 h-history slot stride (elems)
#define YSTR  262144      // 256*1024 y slot stride (elems)

__device__ __forceinline__ u16 f2b(float f) {
  unsigned u = __float_as_uint(f);
  return (u16)((u + 0x7fffu + ((u >> 16) & 1u)) >> 16);   // RNE f32->bf16
}
__device__ __forceinline__ float b2f(u16 u) { return __uint_as_float(((unsigned)u) << 16); }
__device__ __forceinline__ float sigm(float x) { return 1.f / (1.f + __expf(-x)); }
__device__ __forceinline__ float tanh_f(float x) {
  float e = __expf(-2.f * fabsf(x));
  float t = (1.f - e) / (1.f + e);
  return x >= 0.f ? t : -t;
}
// 16B coherent (agent-relaxed atomic) load as MFMA fragment — compiler-managed waits
__device__ __forceinline__ s8v ld16a(const u16* p) {
  union { u64 q[2]; s8v v; } u;
  const u64* s = (const u64*)p;
  u.q[0] = __hip_atomic_load(s,     __ATOMIC_RELAXED, __HIP_MEMORY_SCOPE_AGENT);
  u.q[1] = __hip_atomic_load(s + 1, __ATOMIC_RELAXED, __HIP_MEMORY_SCOPE_AGENT);
  return u.v;
}

// ---------------- f32 -> bf16 row-permuted conversion: dst[tl*256+b] = src[b*T+toff+tl]
__global__ __launch_bounds__(256) void conv_tr(const float* __restrict__ src,
                                               u16* __restrict__ dst, int T, int D, int toff) {
  const int tl = blockIdx.x >> 8, b = blockIdx.x & 255;
  const float* s = src + ((size_t)b * T + toff + tl) * D;
  u16* d = dst + (size_t)blockIdx.x * D;
  for (int i = threadIdx.x * 8; i < D; i += 2048) {
    float4 a = *(const float4*)(s + i);
    float4 c = *(const float4*)(s + i + 4);
    unsigned w0 = (unsigned)f2b(a.x) | ((unsigned)f2b(a.y) << 16);
    unsigned w1 = (unsigned)f2b(a.z) | ((unsigned)f2b(a.w) << 16);
    unsigned w2 = (unsigned)f2b(c.x) | ((unsigned)f2b(c.y) << 16);
    unsigned w3 = (unsigned)f2b(c.z) | ((unsigned)f2b(c.w) << 16);
    *(int4*)(d + i) = make_int4((int)w0, (int)w1, (int)w2, (int)w3);
  }
}

// ---------------- weight pack (f32 -> bf16) --------------------------------------------
__global__ void pack_bf16(u16* __restrict__ dst, int dld, int doff,
                          const float* __restrict__ src, int sld, int soff,
                          int Wc, int R, int Rsrc) {
  int i = blockIdx.x * 256 + threadIdx.x;
  if (i >= Wc * R) return;
  int r = i / Wc, c = i - r * Wc;
  float v = (r < Rsrc) ? src[(size_t)r * sld + soff + c] : 0.f;
  dst[(size_t)r * dld + doff + c] = f2b(v);
}

// ---------------- recurrence weight pack: Wpk[st][cs][lr][k], lr=(q*4+w)*16+fr ---------
__global__ __launch_bounds__(256) void wpack(u16* __restrict__ dst,
                                             const float* __restrict__ Whh1,
                                             const float* __restrict__ Wih2,
                                             const float* __restrict__ Whh2) {
  int idx = blockIdx.x * 256 + threadIdx.x;
  if (idx >= 786432) return;
  int k = idx & 255, lr = (idx >> 8) & 255, cs = (idx >> 16) & 3, st = idx >> 18;
  int q = lr >> 6, w = (lr >> 4) & 3, fr = lr & 15;
  int g = q * 256 + cs * 64 + w * 16 + fr;
  float v = (st == 0) ? Whh1[(size_t)g * 256 + k]
          : (st == 1) ? Wih2[(size_t)g * 512 + 256 + k]
                      : Whh2[(size_t)g * 256 + k];
  dst[idx] = f2b(v);
}

__global__ void bias_setup(const float* __restrict__ bi1, const float* __restrict__ bh1,
                           const float* __restrict__ bi2, const float* __restrict__ bh2,
                           const float* __restrict__ bo,
                           float* __restrict__ b1s, float* __restrict__ b2s,
                           float* __restrict__ bop) {
  int i = blockIdx.x * 256 + threadIdx.x;
  if (i < 1024) { b1s[i] = bi1[i] + bh1[i]; b2s[i] = bi2[i] + bh2[i]; }
  if (i < VOCP) bop[i] = (i < VOC) ? bo[i] : -1e30f;
}

// ---------------- targets = argmax(caption_one_hot[b, d+1, :]) -------------------------
__global__ __launch_bounds__(256) void argmax_kernel(const float* __restrict__ coh,
                                                     int* __restrict__ tgt) {
  const int d = blockIdx.x >> 8;
  const int b = blockIdx.x & 255;
  const float4* row = (const float4*)(coh + ((size_t)b * 40 + (d + 1)) * VOC);
  float best = -3.4e38f; int bi = 0;
  for (int v = threadIdx.x; v < VOC / 4; v += 256) {
    float4 x = row[v];
    float vals[4] = {x.x, x.y, x.z, x.w};
#pragma unroll
    for (int j = 0; j < 4; ++j)
      if (vals[j] > best) { best = vals[j]; bi = v * 4 + j; }
  }
#pragma unroll
  for (int o = 1; o < 64; o <<= 1) {
    float ov = __shfl_xor(best, o);
    int   oi = __shfl_xor(bi, o);
    if (ov > best || (ov == best && oi < bi)) { best = ov; bi = oi; }
  }
  __shared__ float sv[4]; __shared__ int si[4];
  if ((threadIdx.x & 63) == 0) { sv[threadIdx.x >> 6] = best; si[threadIdx.x >> 6] = bi; }
  __syncthreads();
  if (threadIdx.x == 0) {
    for (int i = 1; i < 4; ++i)
      if (sv[i] > best || (sv[i] == best && si[i] < bi)) { best = sv[i]; bi = si[i]; }
    tgt[blockIdx.x] = bi;   // [d][b]
  }
}

// ---------------- GEMM: acc = A_bf16[M][K] * Bw_bf16[N][K]^T (+bias) -------------------
// grid (M/128, N/256). MODE 0: time-major bf16 out (ld 1024, row moff+m).
// MODE 2: fused NLL partials. XCD-bijective swizzle on the m-tile index.
template <int MODE>
__global__ __launch_bounds__(256) void gemm_bb(
    const u16* __restrict__ A, const u16* __restrict__ Bw,
    const float* __restrict__ bias, void* __restrict__ out0,
    float* __restrict__ ps, float* __restrict__ tgtlog, const int* __restrict__ tgt,
    int K, int moff)
{
  const int nx = gridDim.x;
  const int qq = nx >> 3, rm = nx & 7;
  const int xcd = (int)blockIdx.x & 7, pos = (int)blockIdx.x >> 3;
  const int mt = (xcd < rm) ? (xcd * (qq + 1) + pos)
                            : (rm * (qq + 1) + (xcd - rm) * qq + pos);
  const int m0 = mt * 128;
  const int n0 = blockIdx.y * 256;
  const int tid = threadIdx.x;
  const int lane = tid & 63;
  const int wid = tid >> 6;
  const int wm = wid >> 1, wn = wid & 1;
  const int fr = lane & 15;
  const int fk = (lane >> 4) * 8;
  const int rq = lane >> 4;

  __shared__ u16 As[128][72];
  __shared__ u16 Bs[256][72];
  f4v acc[4][8] = {};

  const int ar = tid >> 1, ac = (tid & 1) * 32;
  int4 av[4], bv[8];
  {
    const u16* ap = A + (size_t)(m0 + ar) * K + ac;
    const u16* bp = Bw + (size_t)(n0 + tid) * K;
#pragma unroll
    for (int v = 0; v < 4; ++v) av[v] = *(const int4*)(ap + v * 8);
#pragma unroll
    for (int v = 0; v < 8; ++v) bv[v] = *(const int4*)(bp + v * 8);
  }
#pragma unroll 1
  for (int k0 = 0; k0 < K; k0 += 64) {
    __syncthreads();
#pragma unroll
    for (int v = 0; v < 4; ++v) *(int4*)&As[ar][ac + v * 8] = av[v];
#pragma unroll
    for (int v = 0; v < 8; ++v) *(int4*)&Bs[tid][v * 8] = bv[v];
    __syncthreads();
    if (k0 + 64 < K) {
      const u16* ap = A + (size_t)(m0 + ar) * K + k0 + 64 + ac;
      const u16* bp = Bw + (size_t)(n0 + tid) * K + k0 + 64;
#pragma unroll
      for (int v = 0; v < 4; ++v) av[v] = *(const int4*)(ap + v * 8);
#pragma unroll
      for (int v = 0; v < 8; ++v) bv[v] = *(const int4*)(bp + v * 8);
    }
#pragma unroll
    for (int ks = 0; ks < 2; ++ks) {
      const int kb = ks * 32 + fk;
      s8v a[4], b[8];
#pragma unroll
      for (int i = 0; i < 4; ++i) a[i] = *(const s8v*)&As[wm * 64 + i * 16 + fr][kb];
#pragma unroll
      for (int j = 0; j < 8; ++j) b[j] = *(const s8v*)&Bs[wn * 128 + j * 16 + fr][kb];
#pragma unroll
      for (int i = 0; i < 4; ++i)
#pragma unroll
        for (int j = 0; j < 8; ++j)
          acc[i][j] = __builtin_amdgcn_mfma_f32_16x16x32_bf16(a[i], b[j], acc[i][j], 0, 0, 0);
    }
  }

  float bz[8];
#pragma unroll
  for (int j = 0; j < 8; ++j) bz[j] = bias[n0 + wn * 128 + j * 16 + fr];

  if (MODE == 2) {
    const int tile = blockIdx.y * 2 + wn;
    float* pm = (float*)out0;
#pragma unroll
    for (int i = 0; i < 4; ++i) {
#pragma unroll
      for (int r = 0; r < 4; ++r) {
        const int row = m0 + wm * 64 + i * 16 + rq * 4 + r;
        const int tg = tgt[row];
        float vj[8]; float m = -1e30f;
#pragma unroll
        for (int j = 0; j < 8; ++j) {
          const int n = n0 + wn * 128 + j * 16 + fr;
          float v = acc[i][j][r] + bz[j];
          vj[j] = v;
          m = fmaxf(m, v);
          if (n == tg) tgtlog[row] = v;
        }
#pragma unroll
        for (int o = 1; o < 16; o <<= 1) m = fmaxf(m, __shfl_xor(m, o));
        float s = 0.f;
#pragma unroll
        for (int j = 0; j < 8; ++j) s += __expf(vj[j] - m);
#pragma unroll
        for (int o = 1; o < 16; o <<= 1) s += __shfl_xor(s, o);
        if (fr == 0) { pm[(size_t)row * 48 + tile] = m; ps[(size_t)row * 48 + tile] = s; }
      }
    }
  } else {
    u16* X = (u16*)out0;
#pragma unroll
    for (int i = 0; i < 4; ++i)
#pragma unroll
      for (int r = 0; r < 4; ++r) {
        const int mrow = m0 + wm * 64 + i * 16 + rq * 4 + r;
        u16* crow = X + (size_t)(moff + mrow) * 1024;
#pragma unroll
        for (int j = 0; j < 8; ++j)
          crow[n0 + wn * 128 + j * 16 + fr] = f2b(acc[i][j][r] + bz[j]);
      }
  }
}

// ---------------- 3-stage recurrence ----------------------------------------------------
// 48 blocks x 256 thr (4 waves), 128KB LDS weights each. Stage = bid>>4:
//   A: h1(s) = LSTM1(h1(s-1), X1|b1)          [chain, K=256]
//   B: y(s)  = h1(s) @ Wih2b^T                [no self-chain: pure pipeline]
//   C: h2(s) = LSTM2(h2(s-1), y(s) + Xc|b2)   [chain, K=256]
// Block (rg 0..3, cs 0..3): batch rows rg*64..+64 x h/gate cols cs*64..+64.
// Swapped MFMA mfma(W, h): lane&15 = batch row, (lane>>4)*4+reg = col -> u64 h-stores.
// Histories [120][256][256], slot s+1 = h(s), slot 0 zeroed. ybuf [119][256][1024].
// Publish: atomic u64 stores -> vmcnt(0) -> __syncthreads -> flag (R4-proven protocol).
__global__ __launch_bounds__(256, 1) void recur_kernel(
    const u16* __restrict__ X1t,      // [80][256][1024] bf16, b1 folded
    const u16* __restrict__ Xct,      // [40][256][1024] bf16, b2 folded
    const float* __restrict__ b1sum, const float* __restrict__ b2sum,
    const u16* __restrict__ Wpk,      // [3][4][256][256] packed weights
    u16* __restrict__ h1hist, u16* __restrict__ h2hist,
    u16* __restrict__ ybuf,
    u32* __restrict__ flags)          // fA[16] | fB[16] | fC[16]
{
  __shared__ u16 wlds[256 * 256];     // 128 KiB, XOR-swizzled (granule ^= row&7)
  const int tid = threadIdx.x, lane = tid & 63, w = tid >> 6;
  const int stage = blockIdx.x >> 4, sub = blockIdx.x & 15;
  const int rg = sub >> 2, cs = sub & 3;
  const int fr = lane & 15, rq = lane >> 4;
  u32* fA = flags; u32* fB = flags + 16; u32* fC = flags + 32;

  // one-time: weight slice -> LDS, swizzled
  {
    const u16* wsrc = Wpk + (size_t)(stage * 4 + cs) * 65536;
    for (int i = tid; i < 8192; i += 256) {
      int lr = i >> 5, c8 = i & 31;
      int4 v = *(const int4*)(wsrc + lr * 256 + c8 * 8);
      *(int4*)&wlds[lr * 256 + ((c8 ^ (lr & 7)) * 8)] = v;
    }
  }
  float br[16];
  {
    const float* bs = (stage == 2) ? b2sum : b1sum;
#pragma unroll
    for (int q = 0; q < 4; ++q)
#pragma unroll
      for (int r = 0; r < 4; ++r)
        br[q * 4 + r] = bs[q * 256 + cs * 64 + w * 16 + rq * 4 + r];
  }
  __syncthreads();

  u32* myflag = flags + stage * 16 + sub;
  float creg[4][4] = {};
  const int hcol = cs * 64 + w * 16 + rq * 4;

#pragma unroll 1
  for (int s = 0; s < 119; ++s) {
    if (stage == 0) {                  // ================= A: LSTM1 =================
      u64 xa[4][4];
      if (s < 80) {
        const u16* xb = X1t + ((size_t)s * 256) * 1024;
#pragma unroll
        for (int q = 0; q < 4; ++q)
#pragma unroll
          for (int bt = 0; bt < 4; ++bt)
            xa[q][bt] = *(const u64*)(xb + (size_t)(rg * 64 + bt * 16 + fr) * 1024 +
                                      q * 256 + hcol);
      }
      // poll own group's previous step (s=0 trivially true)
      while (true) {
        bool ok = true;
        if (lane < 4)
          ok = __hip_atomic_load(&fA[rg * 4 + lane], __ATOMIC_RELAXED,
                                 __HIP_MEMORY_SCOPE_AGENT) >= (u32)s;
        if (__all(ok)) break;
        __builtin_amdgcn_s_sleep(1);
      }
      __builtin_amdgcn_sched_barrier(0);
      s8v hb[4][8];
      const u16* hbase = h1hist + (size_t)s * HSTR;
#pragma unroll
      for (int bt = 0; bt < 4; ++bt) {
        const u16* hp = hbase + (size_t)(rg * 64 + bt * 16 + fr) * 256 + rq * 8;
#pragma unroll
        for (int kk = 0; kk < 8; ++kk) hb[bt][kk] = ld16a(hp + kk * 32);
      }
      f4v acc[4][4] = {};
#pragma unroll
      for (int kk = 0; kk < 8; ++kk)
#pragma unroll
        for (int q = 0; q < 4; ++q) {
          s8v wf = *(const s8v*)&wlds[((q * 4 + w) * 16 + fr) * 256 +
                                      (((kk * 4 + rq) ^ (fr & 7)) * 8)];
#pragma unroll
          for (int bt = 0; bt < 4; ++bt)
            acc[q][bt] = __builtin_amdgcn_mfma_f32_16x16x32_bf16(wf, hb[bt][kk],
                                                                 acc[q][bt], 0, 0, 0);
        }
      u16* hw = h1hist + (size_t)(s + 1) * HSTR;
#pragma unroll
      for (int bt = 0; bt < 4; ++bt) {
        u64 hp = 0;
#pragma unroll
        for (int r = 0; r < 4; ++r) {
          float g0 = acc[0][bt][r], g1 = acc[1][bt][r];
          float g2 = acc[2][bt][r], g3 = acc[3][bt][r];
          if (s < 80) {
            g0 += b2f((u16)(xa[0][bt] >> (r * 16)));
            g1 += b2f((u16)(xa[1][bt] >> (r * 16)));
            g2 += b2f((u16)(xa[2][bt] >> (r * 16)));
            g3 += b2f((u16)(xa[3][bt] >> (r * 16)));
          } else { g0 += br[r]; g1 += br[4 + r]; g2 += br[8 + r]; g3 += br[12 + r]; }
          float cn = sigm(g1) * creg[bt][r] + sigm(g0) * tanh_f(g2);
          float h = sigm(g3) * tanh_f(cn);
          creg[bt][r] = cn;
          hp |= (u64)f2b(h) << (r * 16);
        }
        __hip_atomic_store((u64*)(hw + (size_t)(rg * 64 + bt * 16 + fr) * 256 + hcol),
                           hp, __ATOMIC_RELAXED, __HIP_MEMORY_SCOPE_AGENT);
      }
    } else if (stage == 1) {           // ================= B: y = h1 @ Wih2b^T ======
      while (true) {
        bool ok = true;
        if (lane < 4)
          ok = __hip_atomic_load(&fA[rg * 4 + lane], __ATOMIC_RELAXED,
                                 __HIP_MEMORY_SCOPE_AGENT) >= (u32)(s + 1);
        if (__all(ok)) break;
        __builtin_amdgcn_s_sleep(1);
      }
      __builtin_amdgcn_sched_barrier(0);
      s8v hb[4][8];
      const u16* hbase = h1hist + (size_t)(s + 1) * HSTR;
#pragma unroll
      for (int bt = 0; bt < 4; ++bt) {
        const u16* hp = hbase + (size_t)(rg * 64 + bt * 16 + fr) * 256 + rq * 8;
#pragma unroll
        for (int kk = 0; kk < 8; ++kk) hb[bt][kk] = ld16a(hp + kk * 32);
      }
      f4v acc[4][4] = {};
#pragma unroll
      for (int kk = 0; kk < 8; ++kk)
#pragma unroll
        for (int q = 0; q < 4; ++q) {
          s8v wf = *(const s8v*)&wlds[((q * 4 + w) * 16 + fr) * 256 +
                                      (((kk * 4 + rq) ^ (fr & 7)) * 8)];
#pragma unroll
          for (int bt = 0; bt < 4; ++bt)
            acc[q][bt] = __builtin_amdgcn_mfma_f32_16x16x32_bf16(wf, hb[bt][kk],
                                                                 acc[q][bt], 0, 0, 0);
        }
      u16* yw = ybuf + (size_t)s * YSTR;
#pragma unroll
      for (int bt = 0; bt < 4; ++bt)
#pragma unroll
        for (int q = 0; q < 4; ++q) {
          u64 yp = 0;
#pragma unroll
          for (int r = 0; r < 4; ++r) yp |= (u64)f2b(acc[q][bt][r]) << (r * 16);
          __hip_atomic_store((u64*)(yw + (size_t)(rg * 64 + bt * 16 + fr) * 1024 +
                                    q * 256 + hcol),
                             yp, __ATOMIC_RELAXED, __HIP_MEMORY_SCOPE_AGENT);
        }
    } else {                           // ================= C: LSTM2 (K=256) =========
      u64 xa[4][4];
      if (s >= 80) {
        const u16* xb = Xct + ((size_t)(s - 80) * 256) * 1024;
#pragma unroll
        for (int q = 0; q < 4; ++q)
#pragma unroll
          for (int bt = 0; bt < 4; ++bt)
            xa[q][bt] = *(const u64*)(xb + (size_t)(rg * 64 + bt * 16 + fr) * 1024 +
                                      q * 256 + hcol);
      }
      while (true) {
        bool ok = true;
        if (lane < 4)
          ok = __hip_atomic_load(&fC[rg * 4 + lane], __ATOMIC_RELAXED,
                                 __HIP_MEMORY_SCOPE_AGENT) >= (u32)s;
        else if (lane == 4)
          ok = __hip_atomic_load(&fB[rg * 4 + cs], __ATOMIC_RELAXED,
                                 __HIP_MEMORY_SCOPE_AGENT) >= (u32)(s + 1);
        if (__all(ok)) break;
        __builtin_amdgcn_s_sleep(1);
      }
      __builtin_amdgcn_sched_barrier(0);
      u64 ya[4][4];
      {
        const u16* yb = ybuf + (size_t)s * YSTR;
#pragma unroll
        for (int q = 0; q < 4; ++q)
#pragma unroll
          for (int bt = 0; bt < 4; ++bt)
            ya[q][bt] = __hip_atomic_load(
                (const u64*)(yb + (size_t)(rg * 64 + bt * 16 + fr) * 1024 + q * 256 + hcol),
                __ATOMIC_RELAXED, __HIP_MEMORY_SCOPE_AGENT);
      }
      s8v hb[4][8];
      const u16* hbase = h2hist + (size_t)s * HSTR;
#pragma unroll
      for (int bt = 0; bt < 4; ++bt) {
        const u16* hp = hbase + (size_t)(rg * 64 + bt * 16 + fr) * 256 + rq * 8;
#pragma unroll
        for (int kk = 0; kk < 8; ++kk) hb[bt][kk] = ld16a(hp + kk * 32);
      }
      f4v acc[4][4] = {};
#pragma unroll
      for (int kk = 0; kk < 8; ++kk)
#pragma unroll
        for (int q = 0; q < 4; ++q) {
          s8v wf = *(const s8v*)&wlds[((q * 4 + w) * 16 + fr) * 256 +
                                      (((kk * 4 + rq) ^ (fr & 7)) * 8)];
#pragma unroll
          for (int bt = 0; bt < 4; ++bt)
            acc[q][bt] = __builtin_amdgcn_mfma_f32_16x16x32_bf16(wf, hb[bt][kk],
                                                                 acc[q][bt], 0, 0, 0);
        }
      u16* hw = h2hist + (size_t)(s + 1) * HSTR;
#pragma unroll
      for (int bt = 0; bt < 4; ++bt) {
        u64 hp = 0;
#pragma unroll
        for (int r = 0; r < 4; ++r) {
          float g0 = acc[0][bt][r] + b2f((u16)(ya[0][bt] >> (r * 16)));
          float g1 = acc[1][bt][r] + b2f((u16)(ya[1][bt] >> (r * 16)));
          float g2 = acc[2][bt][r] + b2f((u16)(ya[2][bt] >> (r * 16)));
          float g3 = acc[3][bt][r] + b2f((u16)(ya[3][bt] >> (r * 16)));
          if (s >= 80) {
            g0 += b2f((u16)(xa[0][bt] >> (r * 16)));
            g1 += b2f((u16)(xa[1][bt] >> (r * 16)));
            g2 += b2f((u16)(xa[2][bt] >> (r * 16)));
            g3 += b2f((u16)(xa[3][bt] >> (r * 16)));
          } else { g0 += br[r]; g1 += br[4 + r]; g2 += br[8 + r]; g3 += br[12 + r]; }
          float cn = sigm(g1) * creg[bt][r] + sigm(g0) * tanh_f(g2);
          float h = sigm(g3) * tanh_f(cn);
          creg[bt][r] = cn;
          hp |= (u64)f2b(h) << (r * 16);
        }
        __hip_atomic_store((u64*)(hw + (size_t)(rg * 64 + bt * 16 + fr) * 256 + hcol),
                           hp, __ATOMIC_RELAXED, __HIP_MEMORY_SCOPE_AGENT);
      }
    }
    // publish: drain this wave's stores, block-sync, single flag store
    asm volatile("s_waitcnt vmcnt(0)" ::: "memory");
    __syncthreads();
    if (tid == 0)
      __hip_atomic_store(myflag, (u32)(s + 1), __ATOMIC_RELAXED, __HIP_MEMORY_SCOPE_AGENT);
  }
}

// ---------------- combine per-tile LSE partials -> per-row NLL -------------------------
__global__ __launch_bounds__(256) void nll_combine(const float* __restrict__ pm,
                                                   const float* __restrict__ ps,
                                                   const float* __restrict__ tgtlog,
                                                   float* __restrict__ rowloss) {
  int row = blockIdx.x * 256 + threadIdx.x;
  if (row >= 9984) return;
  const float* pmr = pm + (size_t)row * 48;
  const float* psr = ps + (size_t)row * 48;
  float M = -1e30f;
#pragma unroll
  for (int t = 0; t < 48; ++t) M = fmaxf(M, pmr[t]);
  float S = 0.f;
#pragma unroll
  for (int t = 0; t < 48; ++t) S += psr[t] * __expf(pmr[t] - M);
  rowloss[row] = M + __logf(S) - tgtlog[row];
}

__global__ __launch_bounds__(256) void final_kernel(const float* __restrict__ rowloss,
                                                    float* __restrict__ out) {
  float s = 0.f;
  for (int n = threadIdx.x; n < 9984; n += 256) s += rowloss[n];
#pragma unroll
  for (int o = 1; o < 64; o <<= 1) s += __shfl_xor(s, o);
  __shared__ float sr[4];
  if ((threadIdx.x & 63) == 0) sr[threadIdx.x >> 6] = s;
  __syncthreads();
  if (threadIdx.x == 0) out[0] = (sr[0] + sr[1] + sr[2] + sr[3]) * (1.f / 256.f);
}

// ---------------------------------------------------------------------------------------
extern "C" void kernel_launch(void* const* d_in, const int* in_sizes, int n_in,
                              void* d_out, int out_size, void* d_ws, size_t ws_size,
                              hipStream_t stream) {
  const float* feat    = (const float*)d_in[0];
  const float* caption = (const float*)d_in[1];
  const float* coh     = (const float*)d_in[2];
  const float* W_ih1   = (const float*)d_in[3];
  const float* W_hh1   = (const float*)d_in[4];
  const float* b_ih1   = (const float*)d_in[5];
  const float* b_hh1   = (const float*)d_in[6];
  const float* W_ih2   = (const float*)d_in[7];
  const float* W_hh2   = (const float*)d_in[8];
  const float* b_ih2   = (const float*)d_in[9];
  const float* b_hh2   = (const float*)d_in[10];
  const float* W_out   = (const float*)d_in[11];
  const float* b_out   = (const float*)d_in[12];

  char* p = (char*)d_ws;
  auto take = [&](size_t bytes) { char* r = p; p += (bytes + 255) & ~(size_t)255; return r; };
  u16* X1t    = (u16*)take(80ull * 256 * 1024 * 2);    // 41.9 MB, time-major
  u16* Xct    = (u16*)take(40ull * 256 * 1024 * 2);    // 21.0 MB
  u16* h1hist = (u16*)take(120ull * HSTR * 2);         // 15.7 MB
  u16* h2hist = (u16*)take(120ull * HSTR * 2);         // 15.7 MB (slots 81.. = H2dec)
  u16* Wih1b  = (u16*)take(1024ull * 4096 * 2);
  u16* Wih2ab = (u16*)take(1024ull * 256 * 2);
  u16* Woutb  = (u16*)take((size_t)VOCP * 256 * 2);
  u16* Wpk    = (u16*)take(786432ull * 2);             // 1.5 MB packed recur weights
  float* b1sum = (float*)take(1024 * 4);
  float* b2sum = (float*)take(1024 * 4);
  float* boutp = (float*)take(VOCP * 4);
  int*   tgt   = (int*)take(9984 * 4);
  float* tgtlog = (float*)take(9984 * 4);
  float* pm    = (float*)take(9984ull * 48 * 4);
  float* ps    = (float*)take(9984ull * 48 * 4);
  float* rowloss = (float*)take(9984 * 4);
  u32* flags   = (u32*)take(256);                      // fA[16] fB[16] fC[16]
  // union region (84 MB): capT/featT (pre-recurrence) then ybuf (recurrence)
  char* uni = take(10240ull * 4096 * 2);
  u16* capT  = (u16*)uni;
  u16* featT = (u16*)uni;
  u16* ybuf  = (u16*)uni;            // 119 * YSTR * 2 = 62.4 MB

  hipMemsetAsync(h1hist, 0, HSTR * 2, stream);
  hipMemsetAsync(h2hist, 0, HSTR * 2, stream);
  hipMemsetAsync(flags, 0, 256, stream);

  bias_setup<<<dim3(24), dim3(256), 0, stream>>>(b_ih1, b_hh1, b_ih2, b_hh2, b_out,
                                                 b1sum, b2sum, boutp);
  auto pack = [&](u16* dst, int dld, int doff, const float* src, int sld, int soff,
                  int Wc, int R, int Rs) {
    int tot = Wc * R;
    pack_bf16<<<dim3((tot + 255) / 256), dim3(256), 0, stream>>>(dst, dld, doff, src, sld, soff,
                                                                 Wc, R, Rs);
  };
  pack(Wih1b, 4096, 0, W_ih1, 4096, 0, 4096, 1024, 1024);
  pack(Wih2ab, 256, 0, W_ih2, 512, 0, 256, 1024, 1024);     // W_ih2[:, :256]
  pack(Woutb, 256, 0, W_out, 256, 0, 256, VOCP, VOC);
  wpack<<<dim3(3072), dim3(256), 0, stream>>>(Wpk, W_hh1, W_ih2, W_hh2);

  argmax_kernel<<<dim3(39 * 256), dim3(256), 0, stream>>>(coh, tgt);

  // caption -> capT (time-major bf16) -> Xct (b2 folded)
  conv_tr<<<dim3(10240), dim3(256), 0, stream>>>(caption, capT, 40, 256, 0);
  gemm_bb<0><<<dim3(80, 4), dim3(256), 0, stream>>>(capT, Wih2ab, b2sum, Xct,
                                                    nullptr, nullptr, nullptr, 256, 0);
  // feat -> featT (time-major bf16, 2 chunks) -> X1t (b1 folded)
  for (int c = 0; c < 2; ++c) {
    conv_tr<<<dim3(10240), dim3(256), 0, stream>>>(feat, featT, 80, 4096, c * 40);
    gemm_bb<0><<<dim3(80, 4), dim3(256), 0, stream>>>(featT, Wih1b, b1sum, X1t,
                                                      nullptr, nullptr, nullptr, 4096,
                                                      c * 10240);
  }

  // whole 119-step recurrence: 48 blocks (A/B/C stages), watermark pipeline
  recur_kernel<<<dim3(48), dim3(256), 0, stream>>>(X1t, Xct, b1sum, b2sum, Wpk,
                                                   h1hist, h2hist, ybuf, flags);

  // logits GEMM (A = h2 decode slots) with fused LSE partials + target logit
  gemm_bb<2><<<dim3(78, 24), dim3(256), 0, stream>>>(h2hist + 81ull * HSTR, Woutb, boutp, pm,
                                                     ps, tgtlog, tgt, 256, 0);
  nll_combine<<<dim3(39), dim3(256), 0, stream>>>(pm, ps, tgtlog, rowloss);
  final_kernel<<<dim3(1), dim3(256), 0, stream>>>(rowloss, (float*)d_out);
}